// Round 4
// baseline (499.994 us; speedup 1.0000x reference)
//
#include <hip/hip_runtime.h>

#define NUM_NODES 20000
#define NUM_EDGES 640000
#define DIM 128
#define NUM_HEADS 8
#define HEAD_DIM 16
#define NEG_SLOPE 0.01f

typedef __attribute__((ext_vector_type(4))) float float4v;

#define TOTAL (NUM_EDGES * NUM_HEADS)  // 5,120,000
#define HALF (TOTAL / 2)               // 2,560,000 (divisible by 8)

// Order-preserving float <-> uint mapping for atomicMax on signed floats.
__device__ __forceinline__ unsigned f2o(float f) {
    unsigned u = __float_as_uint(f);
    return (u & 0x80000000u) ? ~u : (u | 0x80000000u);
}
__device__ __forceinline__ float o2f(unsigned u) {
    return (u & 0x80000000u) ? __uint_as_float(u & 0x7FFFFFFFu)
                             : __uint_as_float(~u);
}

// edge_index may be int32 (harness contract) or int64 (reference dtype).
// int64 little-endian with values < 2^31 => every odd 32-bit word is zero.
// flag != 0  =>  int32 layout.
__global__ void k_detect(const unsigned* __restrict__ ei_raw, int* __restrict__ flag) {
    if (ei_raw[2 * threadIdx.x + 1] != 0) atomicOr(flag, 1);
}

__device__ __forceinline__ int get_target(const int* __restrict__ ei, int e, int is32) {
    return is32 ? ei[NUM_EDGES + e] : ei[2 * (NUM_EDGES + e)];
}

__device__ __forceinline__ float4v ntload4(const float* p) {
    return __builtin_nontemporal_load((const float4v*)p);
}
__device__ __forceinline__ void ntstore4(float* p, float4v v) {
    __builtin_nontemporal_store(v, (float4v*)p);
}

// K1: two independent (edge,head) chains per thread for memory-level
// parallelism. Fused bit-exact msg copy (non-temporal), dot vs LDS-transposed
// weights (conflict-free), LeakyReLU, score store, atomic segment-max.
__global__ __launch_bounds__(256) void k_score(
    const int* __restrict__ ei,
    const float* __restrict__ msg,         // (E, 128) f32
    const float* __restrict__ xe,          // (N, 128) f32
    const float* __restrict__ wt,          // (8, 32) f32
    float* __restrict__ out_msg,           // (E, 128) f32
    float* __restrict__ scores,            // (E, 8) f32 ws
    unsigned* __restrict__ seg_max,        // (N, 8) ordered-uint ws
    const int* __restrict__ flag)
{
    // Transposed weights: w[j*8 + h] = wt[h*32 + j]  -> lanes (h = lane&7)
    // reading fixed j hit 8 consecutive banks, same-address broadcast.
    __shared__ float w[NUM_HEADS * 2 * HEAD_DIM];
    const int tid = threadIdx.x;
    {
        const int h = tid >> 5, j = tid & 31;
        w[j * 8 + h] = wt[tid];
    }
    __syncthreads();

    const int is32 = *flag;
    const int gid0 = blockIdx.x * 256 + tid;
    const int gid1 = gid0 + HALF;

    const int h = gid0 & 7;          // same for both chains (HALF % 8 == 0)
    const int e0 = gid0 >> 3;
    const int e1 = gid1 >> 3;

    const int t0 = get_target(ei, e0, is32);
    const int t1 = get_target(ei, e1, is32);

    const float* mp0 = msg + (size_t)e0 * DIM + h * HEAD_DIM;
    const float* mp1 = msg + (size_t)e1 * DIM + h * HEAD_DIM;
    const float* xp0 = xe + (size_t)t0 * DIM + h * HEAD_DIM;
    const float* xp1 = xe + (size_t)t1 * DIM + h * HEAD_DIM;

    float4v m0[4], m1[4], x0[4], x1[4];
#pragma unroll
    for (int i = 0; i < 4; i++) m0[i] = ntload4(mp0 + 4 * i);
#pragma unroll
    for (int i = 0; i < 4; i++) m1[i] = ntload4(mp1 + 4 * i);
#pragma unroll
    for (int i = 0; i < 4; i++) x0[i] = *(const float4v*)(xp0 + 4 * i);
#pragma unroll
    for (int i = 0; i < 4; i++) x1[i] = *(const float4v*)(xp1 + 4 * i);

    // Bit-exact fused copies (non-temporal: out is never re-read).
    float* op0 = out_msg + (size_t)e0 * DIM + h * HEAD_DIM;
    float* op1 = out_msg + (size_t)e1 * DIM + h * HEAD_DIM;
#pragma unroll
    for (int i = 0; i < 4; i++) ntstore4(op0 + 4 * i, m0[i]);
#pragma unroll
    for (int i = 0; i < 4; i++) ntstore4(op1 + 4 * i, m1[i]);

    float s0 = 0.f, s1 = 0.f;
#pragma unroll
    for (int i = 0; i < 4; i++)
#pragma unroll
        for (int j = 0; j < 4; j++) {
            const float wm = w[(i * 4 + j) * 8 + h];
            const float wx = w[(16 + i * 4 + j) * 8 + h];
            s0 += m0[i][j] * wm;
            s0 += x0[i][j] * wx;
            s1 += m1[i][j] * wm;
            s1 += x1[i][j] * wx;
        }

    s0 = (s0 >= 0.f) ? s0 : NEG_SLOPE * s0;
    s1 = (s1 >= 0.f) ? s1 : NEG_SLOPE * s1;

    scores[gid0] = s0;
    scores[gid1] = s1;
    atomicMax(&seg_max[t0 * NUM_HEADS + h], f2o(s0));
    atomicMax(&seg_max[t1 * NUM_HEADS + h], f2o(s1));
}

// K2: exp(score - segmax) -> atomic segment sum.
__global__ __launch_bounds__(256) void k_sum(
    const int* __restrict__ ei,
    const float* __restrict__ scores,
    const unsigned* __restrict__ seg_max,
    float* __restrict__ seg_sum,
    const int* __restrict__ flag)
{
    const int gid = blockIdx.x * 256 + threadIdx.x;
    const int h = gid & 7;
    const int e = gid >> 3;

    const int t = get_target(ei, e, *flag);
    const float m = o2f(seg_max[t * NUM_HEADS + h]);
    atomicAdd(&seg_sum[t * NUM_HEADS + h], __expf(scores[gid] - m));
}

// K3: recompute exp, normalize, emit f32 alpha.
__global__ __launch_bounds__(256) void k_div(
    const int* __restrict__ ei,
    const float* __restrict__ scores,
    const unsigned* __restrict__ seg_max,
    const float* __restrict__ seg_sum,
    float* __restrict__ out_alpha,
    const int* __restrict__ flag)
{
    const int gid = blockIdx.x * 256 + threadIdx.x;
    const int h = gid & 7;
    const int e = gid >> 3;

    const int t = get_target(ei, e, *flag);
    const int k = t * NUM_HEADS + h;
    const float ex = __expf(scores[gid] - o2f(seg_max[k]));
    out_alpha[gid] = ex / (seg_sum[k] + 1e-16f);
}

extern "C" void kernel_launch(void* const* d_in, const int* in_sizes, int n_in,
                              void* d_out, int out_size, void* d_ws, size_t ws_size,
                              hipStream_t stream) {
    const int* ei = (const int*)d_in[0];
    const float* msg = (const float*)d_in[1];
    const float* xe = (const float*)d_in[2];
    const float* wt = (const float*)d_in[3];

    float* out_msg = (float*)d_out;                             // (E,128) f32
    float* out_alpha = out_msg + (size_t)NUM_EDGES * DIM;       // (E,8) f32

    char* ws = (char*)d_ws;
    float* scores = (float*)ws;                                 // E*8 f32 = 20.48 MB
    size_t off = (size_t)NUM_EDGES * NUM_HEADS * sizeof(float);
    unsigned* seg_max = (unsigned*)(ws + off);                  // N*8 u32
    float* seg_sum = (float*)(ws + off + (size_t)NUM_NODES * NUM_HEADS * 4);
    int* flag = (int*)(ws + off + (size_t)NUM_NODES * NUM_HEADS * 8);

    // Zero seg_max (ordered-uint 0 < any mapped finite float), seg_sum, flag.
    hipMemsetAsync(seg_max, 0, (size_t)NUM_NODES * NUM_HEADS * 8 + 4, stream);

    k_detect<<<1, 256, 0, stream>>>((const unsigned*)ei, flag);
    k_score<<<HALF / 256, 256, 0, stream>>>(ei, msg, xe, wt, out_msg, scores, seg_max, flag);
    k_sum<<<TOTAL / 256, 256, 0, stream>>>(ei, scores, seg_max, seg_sum, flag);
    k_div<<<TOTAL / 256, 256, 0, stream>>>(ei, scores, seg_max, seg_sum, out_alpha, flag);
}

// Round 5
// 256.801 us; speedup vs baseline: 1.9470x; 1.9470x over previous
//
#include <hip/hip_runtime.h>

#define NUM_NODES 20000
#define NUM_EDGES 640000
#define DIM 128
#define NUM_HEADS 8
#define HEAD_DIM 16
#define NEG_SLOPE 0.01f

typedef __attribute__((ext_vector_type(4))) float float4v;

#define TOTAL (NUM_EDGES * NUM_HEADS)  // 5,120,000
#define HALF (TOTAL / 2)               // 2,560,000 (divisible by 8)

// Order-preserving float <-> uint mapping for atomicMax on signed floats.
__device__ __forceinline__ unsigned f2o(float f) {
    unsigned u = __float_as_uint(f);
    return (u & 0x80000000u) ? ~u : (u | 0x80000000u);
}
__device__ __forceinline__ float o2f(unsigned u) {
    return (u & 0x80000000u) ? __uint_as_float(u & 0x7FFFFFFFu)
                             : __uint_as_float(~u);
}

// edge_index may be int32 (harness contract) or int64 (reference dtype).
// int64 little-endian with values < 2^31 => every odd 32-bit word is zero.
// flag != 0  =>  int32 layout.
__global__ void k_detect(const unsigned* __restrict__ ei_raw, int* __restrict__ flag) {
    if (ei_raw[2 * threadIdx.x + 1] != 0) atomicOr(flag, 1);
}

__device__ __forceinline__ int get_target(const int* __restrict__ ei, int e, int is32) {
    return is32 ? ei[NUM_EDGES + e] : ei[2 * (NUM_EDGES + e)];
}

// K1: two independent (edge,head) chains per thread for memory-level
// parallelism. Fused bit-exact msg copy (regular stores -> L2 write
// coalescing), dot vs LDS-transposed weights, LeakyReLU, score store,
// atomic segment-max.
__global__ __launch_bounds__(256) void k_score(
    const int* __restrict__ ei,
    const float* __restrict__ msg,         // (E, 128) f32
    const float* __restrict__ xe,          // (N, 128) f32
    const float* __restrict__ wt,          // (8, 32) f32
    float* __restrict__ out_msg,           // (E, 128) f32
    float* __restrict__ scores,            // (E, 8) f32 ws
    unsigned* __restrict__ seg_max,        // (N, 8) ordered-uint ws
    const int* __restrict__ flag)
{
    // Transposed weights: w[j*8 + h] = wt[h*32 + j]  -> lanes (h = lane&7)
    // reading fixed j hit 8 consecutive banks, same-address broadcast.
    __shared__ float w[NUM_HEADS * 2 * HEAD_DIM];
    const int tid = threadIdx.x;
    {
        const int h = tid >> 5, j = tid & 31;
        w[j * 8 + h] = wt[tid];
    }
    __syncthreads();

    const int is32 = *flag;
    const int gid0 = blockIdx.x * 256 + tid;
    const int gid1 = gid0 + HALF;

    const int h = gid0 & 7;          // same for both chains (HALF % 8 == 0)
    const int e0 = gid0 >> 3;
    const int e1 = gid1 >> 3;

    const int t0 = get_target(ei, e0, is32);
    const int t1 = get_target(ei, e1, is32);

    const float* mp0 = msg + (size_t)e0 * DIM + h * HEAD_DIM;
    const float* mp1 = msg + (size_t)e1 * DIM + h * HEAD_DIM;
    const float* xp0 = xe + (size_t)t0 * DIM + h * HEAD_DIM;
    const float* xp1 = xe + (size_t)t1 * DIM + h * HEAD_DIM;

    float4v m0[4], m1[4], x0[4], x1[4];
#pragma unroll
    for (int i = 0; i < 4; i++) m0[i] = *(const float4v*)(mp0 + 4 * i);
#pragma unroll
    for (int i = 0; i < 4; i++) m1[i] = *(const float4v*)(mp1 + 4 * i);
#pragma unroll
    for (int i = 0; i < 4; i++) x0[i] = *(const float4v*)(xp0 + 4 * i);
#pragma unroll
    for (int i = 0; i < 4; i++) x1[i] = *(const float4v*)(xp1 + 4 * i);

    // Bit-exact fused copies (regular stores: L2 merges the 16B fragments
    // into full lines before eviction).
    float* op0 = out_msg + (size_t)e0 * DIM + h * HEAD_DIM;
    float* op1 = out_msg + (size_t)e1 * DIM + h * HEAD_DIM;
#pragma unroll
    for (int i = 0; i < 4; i++) *(float4v*)(op0 + 4 * i) = m0[i];
#pragma unroll
    for (int i = 0; i < 4; i++) *(float4v*)(op1 + 4 * i) = m1[i];

    float s0 = 0.f, s1 = 0.f;
#pragma unroll
    for (int i = 0; i < 4; i++)
#pragma unroll
        for (int j = 0; j < 4; j++) {
            const float wm = w[(i * 4 + j) * 8 + h];
            const float wx = w[(16 + i * 4 + j) * 8 + h];
            s0 += m0[i][j] * wm;
            s0 += x0[i][j] * wx;
            s1 += m1[i][j] * wm;
            s1 += x1[i][j] * wx;
        }

    s0 = (s0 >= 0.f) ? s0 : NEG_SLOPE * s0;
    s1 = (s1 >= 0.f) ? s1 : NEG_SLOPE * s1;

    scores[gid0] = s0;
    scores[gid1] = s1;
    atomicMax(&seg_max[t0 * NUM_HEADS + h], f2o(s0));
    atomicMax(&seg_max[t1 * NUM_HEADS + h], f2o(s1));
}

// K2: exp(score - segmax) -> atomic segment sum.
__global__ __launch_bounds__(256) void k_sum(
    const int* __restrict__ ei,
    const float* __restrict__ scores,
    const unsigned* __restrict__ seg_max,
    float* __restrict__ seg_sum,
    const int* __restrict__ flag)
{
    const int gid = blockIdx.x * 256 + threadIdx.x;
    const int h = gid & 7;
    const int e = gid >> 3;

    const int t = get_target(ei, e, *flag);
    const float m = o2f(seg_max[t * NUM_HEADS + h]);
    atomicAdd(&seg_sum[t * NUM_HEADS + h], __expf(scores[gid] - m));
}

// K3: recompute exp, normalize, emit f32 alpha.
__global__ __launch_bounds__(256) void k_div(
    const int* __restrict__ ei,
    const float* __restrict__ scores,
    const unsigned* __restrict__ seg_max,
    const float* __restrict__ seg_sum,
    float* __restrict__ out_alpha,
    const int* __restrict__ flag)
{
    const int gid = blockIdx.x * 256 + threadIdx.x;
    const int h = gid & 7;
    const int e = gid >> 3;

    const int t = get_target(ei, e, *flag);
    const int k = t * NUM_HEADS + h;
    const float ex = __expf(scores[gid] - o2f(seg_max[k]));
    out_alpha[gid] = ex / (seg_sum[k] + 1e-16f);
}

extern "C" void kernel_launch(void* const* d_in, const int* in_sizes, int n_in,
                              void* d_out, int out_size, void* d_ws, size_t ws_size,
                              hipStream_t stream) {
    const int* ei = (const int*)d_in[0];
    const float* msg = (const float*)d_in[1];
    const float* xe = (const float*)d_in[2];
    const float* wt = (const float*)d_in[3];

    float* out_msg = (float*)d_out;                             // (E,128) f32
    float* out_alpha = out_msg + (size_t)NUM_EDGES * DIM;       // (E,8) f32

    char* ws = (char*)d_ws;
    float* scores = (float*)ws;                                 // E*8 f32 = 20.48 MB
    size_t off = (size_t)NUM_EDGES * NUM_HEADS * sizeof(float);
    unsigned* seg_max = (unsigned*)(ws + off);                  // N*8 u32
    float* seg_sum = (float*)(ws + off + (size_t)NUM_NODES * NUM_HEADS * 4);
    int* flag = (int*)(ws + off + (size_t)NUM_NODES * NUM_HEADS * 8);

    // Zero seg_max (ordered-uint 0 < any mapped finite float), seg_sum, flag.
    hipMemsetAsync(seg_max, 0, (size_t)NUM_NODES * NUM_HEADS * 8 + 4, stream);

    k_detect<<<1, 256, 0, stream>>>((const unsigned*)ei, flag);
    k_score<<<HALF / 256, 256, 0, stream>>>(ei, msg, xe, wt, out_msg, scores, seg_max, flag);
    k_sum<<<TOTAL / 256, 256, 0, stream>>>(ei, scores, seg_max, seg_sum, flag);
    k_div<<<TOTAL / 256, 256, 0, stream>>>(ei, scores, seg_max, seg_sum, out_alpha, flag);
}